// Round 10
// baseline (505.703 us; speedup 1.0000x reference)
//
#include <hip/hip_runtime.h>
#include <hip/hip_bf16.h>

// Problem constants (fixed by reference)
#define IN_F   4096
#define OUT_F  4096
#define RANK   16
#define M_TOK  8192          // 4 * 2048 tokens
#define SCALING 2.0f         // ALPHA / RANK = 32/16

typedef __attribute__((ext_vector_type(8)))  short short8;   // 8 bf16 = 4 VGPRs
typedef __attribute__((ext_vector_type(4)))  float f32x4;
typedef __attribute__((ext_vector_type(16))) float f32x16;   // 32x32 MFMA acc
typedef __attribute__((ext_vector_type(4)))  float fvec4;
typedef __attribute__((ext_vector_type(4)))  int   ivec4;
typedef __attribute__((ext_vector_type(4)))  unsigned int uvec4;

// ---------------------------------------------------------------------------
// cvt: x fp32 -> bf16, grid-stride streaming (192 MB HBM, ~36 us measured).
// ---------------------------------------------------------------------------
__global__ __launch_bounds__(256) void cvt_x(const float* __restrict__ x,
                                             __hip_bfloat16* __restrict__ xb) {
    const size_t nvec = (size_t)M_TOK * IN_F / 8;
    const size_t stride = (size_t)gridDim.x * 256;
    for (size_t idx = (size_t)blockIdx.x * 256 + threadIdx.x; idx < nvec; idx += stride) {
        const size_t i = idx * 8;
        fvec4 a = __builtin_nontemporal_load((const fvec4*)(x + i));
        fvec4 b = __builtin_nontemporal_load((const fvec4*)(x + i + 4));
        union { uvec4 u; __hip_bfloat16 h[8]; } p;
        p.h[0] = __float2bfloat16(a.x);
        p.h[1] = __float2bfloat16(a.y);
        p.h[2] = __float2bfloat16(a.z);
        p.h[3] = __float2bfloat16(a.w);
        p.h[4] = __float2bfloat16(b.x);
        p.h[5] = __float2bfloat16(b.y);
        p.h[6] = __float2bfloat16(b.z);
        p.h[7] = __float2bfloat16(b.w);
        *(uvec4*)(xb + i) = p.u;              // normal store: GEMM re-reads 16x
    }
}

// ---------------------------------------------------------------------------
// dequant + LoRA fold: W'[o,i] = (q-8)*scale + 2*(lB@lA)[o,i].  (~25 us)
// ---------------------------------------------------------------------------
__global__ __launch_bounds__(256) void dequant_lora(const int* __restrict__ q,
                                                    const float* __restrict__ sc,
                                                    const float* __restrict__ lA,
                                                    const float* __restrict__ lB,
                                                    __hip_bfloat16* __restrict__ W) {
    const int tid = threadIdx.x;
    const int id  = blockIdx.x;              // 0..2047
    const int c0  = (id & 3) * 1024 + tid * 4;
    const int o0  = (id >> 2) * 8;

    ivec4 qv[8];
#pragma unroll
    for (int oo = 0; oo < 8; ++oo)           // all 8 HBM loads in flight
        qv[oo] = __builtin_nontemporal_load(
            (const ivec4*)(q + (size_t)(o0 + oo) * IN_F + c0));

    float sv[8];
#pragma unroll
    for (int oo = 0; oo < 8; ++oo)
        sv[oo] = sc[(o0 + oo) * (IN_F / 64) + (c0 >> 6)];

    fvec4 a[RANK];
#pragma unroll
    for (int r = 0; r < RANK; ++r)           // L2-resident after first touch
        a[r] = *(const fvec4*)(lA + (size_t)r * IN_F + c0);

#pragma unroll
    for (int oo = 0; oo < 8; ++oo) {
        const float* lbo = lB + (size_t)(o0 + oo) * RANK;   // uniform -> SMEM
        float l0 = 0.f, l1 = 0.f, l2 = 0.f, l3 = 0.f;
#pragma unroll
        for (int r = 0; r < RANK; ++r) {
            const float br = lbo[r];
            l0 += br * a[r].x; l1 += br * a[r].y;
            l2 += br * a[r].z; l3 += br * a[r].w;
        }
        const float s = sv[oo];
        union { ushort4 u; __hip_bfloat16 h[4]; } p;
        p.h[0] = __float2bfloat16((float)(qv[oo].x - 8) * s + SCALING * l0);
        p.h[1] = __float2bfloat16((float)(qv[oo].y - 8) * s + SCALING * l1);
        p.h[2] = __float2bfloat16((float)(qv[oo].z - 8) * s + SCALING * l2);
        p.h[3] = __float2bfloat16((float)(qv[oo].w - 8) * s + SCALING * l3);
        *(ushort4*)(W + (size_t)(o0 + oo) * IN_F + c0) = p.u;
    }
}

// ---------------------------------------------------------------------------
// GEMM: C[M,N] = A[M,K](bf16) * B[N,K]^T(bf16) + bias
// r3-verified sync skeleton (4 phases/K-tile, counted vmcnt(4), setprio,
// XCD 8x8 chunk, literal double-buffer) -- UNCHANGED.
// MFMA shape 32x32x16 (m119: 2495 vs 2176 TF for 16x16x32).
// RETRY of round 8: full audit found no fault mechanism (all LDS addrs
// <131072, all global addrs in-bounds, k-order errors cancel A-vs-B,
// row-map errors would be absmax fails not aborts, VGPR ~222 < 256 cap).
// The r8 "Aborted" at pytest=7.1s is suspected infra flake; this retry
// discriminates.  Second failure => permanent revert to r9 config.
//
//   * acc: f32x16[4][2] per wave (4 row-frags x 2 col-frags of 32x32).
//   * LDS halves: 16 subtiles of 32r x 16k (1 KB), LINEAR row-major.
//     A wave's b128 frag read (byte = (l&31)*32 + (l>>5)*16) covers all 64
//     16B units of a subtile exactly once -> conflict-free, no XOR needed.
//   * Staging source for the linear dest: lane l supplies row (l>>1),
//     k-half (l&1) of wave w's subtile (rows (w>>2)*32, k-block (w&3)*16);
//     second load = +64 rows -> subtiles 8..15.
//   * Fragment lane layout (32x32x16 bf16): row = l&31, k-chunk = (l>>5)*8.
//   * C/D layout (m74/m101-verified): col = lane&31,
//     row = (reg&3) + 8*(reg>>2) + 4*(lane>>5), reg in [0,16).
// Phase schedule per K-tile t (gray order over the 2x2 fragment quadrants):
//   ph0: ds A(rb01)x8 + B(cb0)x4; stage A0(t+1)->other buf ; 8 MFMA [rb01,cb0]
//   ph1: ds B(cb1)x4;             stage A1(t+1)->other buf ; 8 MFMA [rb01,cb1]
//   ph2: ds A(rb23)x8;            stage B0(t+2)->cur (dead); 8 MFMA [rb23,cb1]
//   ph3: (no ds);                 stage B1(t+2); vmcnt(4)  ; 8 MFMA [rb23,cb0]
// vmcnt ledger identical to r3: newest load needed for t+1 = A1(t+1) (ph1);
// issued after it = B0,B1(t+2) = 4 -> s_waitcnt vmcnt(4). Never 0 in loop.
// ---------------------------------------------------------------------------

__device__ __forceinline__ void load_lds16(const void* g, void* l) {
    __builtin_amdgcn_global_load_lds(
        (const __attribute__((address_space(1))) unsigned int*)g,
        (__attribute__((address_space(3))) unsigned int*)l, 16, 0, 0);
}

#define MFMA32 __builtin_amdgcn_mfma_f32_32x32x16_bf16

__global__ __launch_bounds__(512, 2) void gemm256_8ph(const __hip_bfloat16* __restrict__ A,
                                                      const __hip_bfloat16* __restrict__ B,
                                                      const float* __restrict__ bias,
                                                      float* __restrict__ C) {
    extern __shared__ __align__(16) char lds[];

    const int tid  = threadIdx.x;
    const int lane = tid & 63;
    const int wave = tid >> 6;

    // T1: XCD swizzle, 8x8 square chunk per XCD (512 wgs % 8 == 0, bijective).
    const int xcd = blockIdx.x & 7;
    const int w64 = blockIdx.x >> 3;               // 0..63 within XCD
    const int tm  = (xcd >> 1) * 8 + (w64 >> 3);   // 0..31 M-tiles
    const int tn  = (xcd & 1) * 8 + (w64 & 7);     // 0..15 N-tiles

    const __hip_bfloat16* Ab = A + (size_t)tm * 256 * IN_F;
    const __hip_bfloat16* Bb = B + (size_t)tn * 256 * IN_F;

    // Staging source for the linear 32rx16k subtile layout:
    // wave w owns subtile si=w (rows (w>>2)*32..+31, k (w&3)*16..+15) and
    // si=w+8 (rows +64).  Lane l supplies 16B: row (l>>1), k-half (l&1).
    const size_t off0 = (size_t)((wave >> 2) * 32 + (lane >> 1)) * IN_F
                      + (size_t)((wave & 3) * 16 + (lane & 1) * 8);

    // Global source stream bases (per-lane, advance by scalar t-offset only)
    const __hip_bfloat16* qA0 = Ab + off0;
    const __hip_bfloat16* qA1 = Ab + (size_t)128 * IN_F + off0;
    const __hip_bfloat16* qB0 = Bb + off0;
    const __hip_bfloat16* qB1 = Bb + (size_t)128 * IN_F + off0;

    // Fragment-read lane offset within a 1 KiB subtile (linear, no swizzle):
    // row = lane&31 (32B stride), k-unit = lane>>5 (16B) -> full 64-unit cover.
    const int lrd = (lane & 31) * 32 + (lane >> 5) * 16;

    const int ah = wave >> 2;          // A half this wave reads (rows)
    const int bh = (wave >> 1) & 1;    // B half this wave reads (cols)

    // Pre-folded LDS read bases per buffer: every read is base + literal.
    const char* aRd[2] = { lds + ah * 16384 + lrd,
                           lds + 65536 + ah * 16384 + lrd };
    const char* bRd[2] = { lds + 32768 + bh * 16384 + (wave & 1) * 8192 + lrd,
                           lds + 65536 + 32768 + bh * 16384 + (wave & 1) * 8192 + lrd };

    const int wv1024 = wave * 1024;    // staging dest subtile base

#define STAGE2(ps, te, LO) do {                                             \
        const __hip_bfloat16* g_ = (ps) + (te);                             \
        load_lds16(g_,              lds + (LO) + wv1024);                   \
        load_lds16(g_ + 64 * IN_F,  lds + (LO) + 8192 + wv1024);            \
    } while (0)

    // ---- prologue: B0(0) B1(0) A0(0) A1(0) B0(1) B1(1)  (12 loads) ----
    STAGE2(qB0, 0,  32768);
    STAGE2(qB1, 0,  49152);
    STAGE2(qA0, 0,  0);
    STAGE2(qA1, 0,  16384);
    STAGE2(qB0, 64, 65536 + 32768);
    STAGE2(qB1, 64, 65536 + 49152);
    asm volatile("s_waitcnt vmcnt(4)" ::: "memory");   // tile0 landed; B(1) in flight
    __builtin_amdgcn_s_barrier();

    short8 aF[2][4], bA[4], bB[4];
    f32x16 acc[4][2] = {};

#define TILE(T, CBI) do {                                                          \
        const int t1e = (((T) + 1) & 63) << 6;   /* elem offset of tile T+1 */     \
        const int t2e = (((T) + 2) & 63) << 6;                                     \
        /* ---------- phase 0: quadrant (rb01, cb0) ---------- */                  \
        _Pragma("unroll")                                                          \
        for (int i = 0; i < 2; ++i)                                                \
            _Pragma("unroll")                                                      \
            for (int ks = 0; ks < 4; ++ks)                                         \
                aF[i][ks] = *(const short8*)(aRd[CBI] + (i * 4 + ks) * 1024);      \
        _Pragma("unroll")                                                          \
        for (int ks = 0; ks < 4; ++ks)                                             \
            bA[ks] = *(const short8*)(bRd[CBI] + ks * 1024);                       \
        STAGE2(qA0, t1e, ((CBI) ^ 1) * 65536);                                     \
        __builtin_amdgcn_s_barrier();                                              \
        __builtin_amdgcn_s_setprio(1);                                             \
        _Pragma("unroll")                                                          \
        for (int ks = 0; ks < 4; ++ks) {                                           \
            acc[0][0] = MFMA32(aF[0][ks], bA[ks], acc[0][0], 0, 0, 0);             \
            acc[1][0] = MFMA32(aF[1][ks], bA[ks], acc[1][0], 0, 0, 0);             \
        }                                                                          \
        __builtin_amdgcn_s_setprio(0);                                             \
        __builtin_amdgcn_s_barrier();                                              \
        /* ---------- phase 1: quadrant (rb01, cb1) ---------- */                  \
        _Pragma("unroll")                                                          \
        for (int ks = 0; ks < 4; ++ks)                                             \
            bB[ks] = *(const short8*)(bRd[CBI] + 4096 + ks * 1024);                \
        STAGE2(qA1, t1e, ((CBI) ^ 1) * 65536 + 16384);                             \
        __builtin_amdgcn_s_barrier();                                              \
        __builtin_amdgcn_s_setprio(1);                                             \
        _Pragma("unroll")                                                          \
        for (int ks = 0; ks < 4; ++ks) {                                           \
            acc[0][1] = MFMA32(aF[0][ks], bB[ks], acc[0][1], 0, 0, 0);             \
            acc[1][1] = MFMA32(aF[1][ks], bB[ks], acc[1][1], 0, 0, 0);             \
        }                                                                          \
        __builtin_amdgcn_s_setprio(0);                                             \
        __builtin_amdgcn_s_barrier();                                              \
        /* ---------- phase 2: quadrant (rb23, cb1) ---------- */                  \
        _Pragma("unroll")                                                          \
        for (int i = 0; i < 2; ++i)                                                \
            _Pragma("unroll")                                                      \
            for (int ks = 0; ks < 4; ++ks)                                         \
                aF[i][ks] = *(const short8*)(aRd[CBI] + 8192 + (i * 4 + ks) * 1024);\
        STAGE2(qB0, t2e, (CBI) * 65536 + 32768);   /* cur-B dead after ph1 */      \
        __builtin_amdgcn_s_barrier();                                              \
        __builtin_amdgcn_s_setprio(1);                                             \
        _Pragma("unroll")                                                          \
        for (int ks = 0; ks < 4; ++ks) {                                           \
            acc[2][1] = MFMA32(aF[0][ks], bB[ks], acc[2][1], 0, 0, 0);             \
            acc[3][1] = MFMA32(aF[1][ks], bB[ks], acc[3][1], 0, 0, 0);             \
        }                                                                          \
        __builtin_amdgcn_s_setprio(0);                                             \
        __builtin_amdgcn_s_barrier();                                              \
        /* ---------- phase 3: quadrant (rb23, cb0) ---------- */                  \
        STAGE2(qB1, t2e, (CBI) * 65536 + 49152);                                   \
        asm volatile("s_waitcnt vmcnt(4)" ::: "memory");  /* tile T+1 landed */    \
        __builtin_amdgcn_s_barrier();                     /* publish to all */     \
        __builtin_amdgcn_s_setprio(1);                                             \
        _Pragma("unroll")                                                          \
        for (int ks = 0; ks < 4; ++ks) {                                           \
            acc[2][0] = MFMA32(aF[0][ks], bA[ks], acc[2][0], 0, 0, 0);             \
            acc[3][0] = MFMA32(aF[1][ks], bA[ks], acc[3][0], 0, 0, 0);             \
        }                                                                          \
        __builtin_amdgcn_s_setprio(0);                                             \
        __builtin_amdgcn_s_barrier();                                              \
    } while (0)

    for (int tt = 0; tt < 32; ++tt) {      // 2 K-tiles per iter: literal buffers
        TILE(2 * tt,     0);
        TILE(2 * tt + 1, 1);
    }
    asm volatile("s_waitcnt vmcnt(0)" ::: "memory");  // drain wrapped prefetches

    // ---- epilogue: 32x32 C/D layout: col = lane&31,
    //      row = (reg&3) + 8*(reg>>2) + 4*(lane>>5); fuse bias. ----
    const int cl = lane & 31;
    const int hi = lane >> 5;
    const size_t m_base = (size_t)tm * 256 + (size_t)ah * 128 + hi * 4;
    const int    n_base = tn * 256 + (wave & 3) * 64;
#pragma unroll
    for (int cb = 0; cb < 2; ++cb) {
        const int n = n_base + cb * 32 + cl;
        const float bv = bias[n];
#pragma unroll
        for (int rb = 0; rb < 4; ++rb) {
#pragma unroll
            for (int g = 0; g < 4; ++g) {
                const size_t m0 = m_base + rb * 32 + g * 8;
#pragma unroll
                for (int rr = 0; rr < 4; ++rr)
                    __builtin_nontemporal_store(acc[rb][cb][g * 4 + rr] + bv,
                                                &C[(m0 + rr) * OUT_F + n]);
            }
        }
    }
#undef STAGE2
#undef TILE
}

// ---------------------------------------------------------------------------
extern "C" void kernel_launch(void* const* d_in, const int* in_sizes, int n_in,
                              void* d_out, int out_size, void* d_ws, size_t ws_size,
                              hipStream_t stream) {
    const float* x    = (const float*)d_in[0];   // [4,2048,4096] fp32
    const int*   qc   = (const int*)d_in[1];     // [4096,4096] int32 codes
    const float* sc   = (const float*)d_in[2];   // [4096,64] fp32
    const float* bias = (const float*)d_in[3];   // [4096]
    const float* lA   = (const float*)d_in[4];   // [16,4096]
    const float* lB   = (const float*)d_in[5];   // [4096,16]
    float* out = (float*)d_out;                  // [4,2048,4096] fp32

    // workspace: x_bf16 (64 MB) + W'_bf16 (32 MB) = 96 MB
    __hip_bfloat16* xb = (__hip_bfloat16*)d_ws;
    __hip_bfloat16* wb = xb + (size_t)M_TOK * IN_F;

    // allow 128 KiB dynamic LDS for the 8-phase GEMM (host-side, capture-safe)
    static bool attr_done = false;
    if (!attr_done) {
        (void)hipFuncSetAttribute((const void*)gemm256_8ph,
                                  hipFuncAttributeMaxDynamicSharedMemorySize, 131072);
        attr_done = true;
    }

    cvt_x<<<2048, 256, 0, stream>>>(x, xb);
    dequant_lora<<<2048, 256, 0, stream>>>(qc, sc, lA, lB, wb);
    gemm256_8ph<<<dim3(512), dim3(512), 131072, stream>>>(xb, wb, bias, out);
}

// Round 11
// 490.663 us; speedup vs baseline: 1.0307x; 1.0307x over previous
//
#include <hip/hip_runtime.h>
#include <hip/hip_bf16.h>

// Problem constants (fixed by reference)
#define IN_F   4096
#define OUT_F  4096
#define RANK   16
#define M_TOK  8192          // 4 * 2048 tokens
#define SCALING 2.0f         // ALPHA / RANK = 32/16

typedef __attribute__((ext_vector_type(8)))  short short8;   // 8 bf16 = 4 VGPRs
typedef __attribute__((ext_vector_type(4)))  float f32x4;
typedef __attribute__((ext_vector_type(16))) float f32x16;   // 32x32 MFMA acc
typedef __attribute__((ext_vector_type(4)))  float fvec4;
typedef __attribute__((ext_vector_type(4)))  int   ivec4;
typedef __attribute__((ext_vector_type(4)))  unsigned int uvec4;

// ---------------------------------------------------------------------------
// cvt: x fp32 -> bf16, grid-stride streaming (192 MB HBM, ~36 us measured).
// ---------------------------------------------------------------------------
__global__ __launch_bounds__(256) void cvt_x(const float* __restrict__ x,
                                             __hip_bfloat16* __restrict__ xb) {
    const size_t nvec = (size_t)M_TOK * IN_F / 8;
    const size_t stride = (size_t)gridDim.x * 256;
    for (size_t idx = (size_t)blockIdx.x * 256 + threadIdx.x; idx < nvec; idx += stride) {
        const size_t i = idx * 8;
        fvec4 a = __builtin_nontemporal_load((const fvec4*)(x + i));
        fvec4 b = __builtin_nontemporal_load((const fvec4*)(x + i + 4));
        union { uvec4 u; __hip_bfloat16 h[8]; } p;
        p.h[0] = __float2bfloat16(a.x);
        p.h[1] = __float2bfloat16(a.y);
        p.h[2] = __float2bfloat16(a.z);
        p.h[3] = __float2bfloat16(a.w);
        p.h[4] = __float2bfloat16(b.x);
        p.h[5] = __float2bfloat16(b.y);
        p.h[6] = __float2bfloat16(b.z);
        p.h[7] = __float2bfloat16(b.w);
        *(uvec4*)(xb + i) = p.u;              // normal store: GEMM re-reads 16x
    }
}

// ---------------------------------------------------------------------------
// dequant + LoRA fold: W'[o,i] = (q-8)*scale + 2*(lB@lA)[o,i].  (~25 us)
// ---------------------------------------------------------------------------
__global__ __launch_bounds__(256) void dequant_lora(const int* __restrict__ q,
                                                    const float* __restrict__ sc,
                                                    const float* __restrict__ lA,
                                                    const float* __restrict__ lB,
                                                    __hip_bfloat16* __restrict__ W) {
    const int tid = threadIdx.x;
    const int id  = blockIdx.x;              // 0..2047
    const int c0  = (id & 3) * 1024 + tid * 4;
    const int o0  = (id >> 2) * 8;

    ivec4 qv[8];
#pragma unroll
    for (int oo = 0; oo < 8; ++oo)           // all 8 HBM loads in flight
        qv[oo] = __builtin_nontemporal_load(
            (const ivec4*)(q + (size_t)(o0 + oo) * IN_F + c0));

    float sv[8];
#pragma unroll
    for (int oo = 0; oo < 8; ++oo)
        sv[oo] = sc[(o0 + oo) * (IN_F / 64) + (c0 >> 6)];

    fvec4 a[RANK];
#pragma unroll
    for (int r = 0; r < RANK; ++r)           // L2-resident after first touch
        a[r] = *(const fvec4*)(lA + (size_t)r * IN_F + c0);

#pragma unroll
    for (int oo = 0; oo < 8; ++oo) {
        const float* lbo = lB + (size_t)(o0 + oo) * RANK;   // uniform -> SMEM
        float l0 = 0.f, l1 = 0.f, l2 = 0.f, l3 = 0.f;
#pragma unroll
        for (int r = 0; r < RANK; ++r) {
            const float br = lbo[r];
            l0 += br * a[r].x; l1 += br * a[r].y;
            l2 += br * a[r].z; l3 += br * a[r].w;
        }
        const float s = sv[oo];
        union { ushort4 u; __hip_bfloat16 h[4]; } p;
        p.h[0] = __float2bfloat16((float)(qv[oo].x - 8) * s + SCALING * l0);
        p.h[1] = __float2bfloat16((float)(qv[oo].y - 8) * s + SCALING * l1);
        p.h[2] = __float2bfloat16((float)(qv[oo].z - 8) * s + SCALING * l2);
        p.h[3] = __float2bfloat16((float)(qv[oo].w - 8) * s + SCALING * l3);
        *(ushort4*)(W + (size_t)(o0 + oo) * IN_F + c0) = p.u;
    }
}

// ---------------------------------------------------------------------------
// GEMM: C[M,N] = A[M,K](bf16) * B[N,K]^T(bf16) + bias
// r3-verified sync skeleton (4 phases/K-tile, counted vmcnt(4), setprio,
// XCD 8x8 chunk, literal double-buffer) + 32x32x16 MFMA (r10: correctness
// verified, absmax 0.125).
//
// ROUND-11 FIX: r10's LDS layout had 2.5e7 bank conflicts (byte bank-group
// bits 4-6 came from lane bits {5,0,1}; lane strides 4/8/16 all aliased).
// New layout = bit permutation with r3's MEASURED-ZERO-CONFLICT bank profile:
// within each 16KB half (R=row 0..127, kc=k-elem 0..63):
//   bits1-3 = kc0-2 | bit4 = R4 | bit5 = kc3^R3 | bit6 = R0
//   bits7-9 = R1-3  | bits10-11 = kc4-5 | bits12-13 = R5-6
// Fragment read (R = rb*32+(l&31), kc = ks*16+(l>>5)*8):
//   addr = flo32 + ks*1024 + rb*4096,
//   flo32 = (l&16) + ((((l>>5)^(l>>3))&1)<<5) + ((l&15)<<6)... (see code);
//   bank-group bits (4,5,6) = (l4, l5^l3, l0)  == r3's zero-conflict profile.
// Staging (global_load_lds, linear dest LO + w*1024 + lane*16, +8192 2nd):
//   inverse mapping -> lane l of wave w sources
//   row  = ((l>>2)&15) + ((l&1)<<4) + ((w>>2)<<5)   (+64 for 2nd load)
//   kc   = (((l>>1)^(l>>5))&1)*8 + (w&3)*16
// Phase schedule per K-tile t (identical barriers/vmcnt to r3):
//   ph0: ds A(rb01)x8 + B(cb0)x4; stage A0(t+1)->other buf ; 8 MFMA [rb01,cb0]
//   ph1: ds B(cb1)x4;             stage A1(t+1)->other buf ; 8 MFMA [rb01,cb1]
//   ph2: ds A(rb23)x8;            stage B0(t+2)->cur (dead); 8 MFMA [rb23,cb1]
//   ph3: (no ds);                 stage B1(t+2); vmcnt(4)  ; 8 MFMA [rb23,cb0]
// vmcnt ledger identical to r3 (never 0 in loop).
// Pre-commit: if gemm >= 244 us or conflicts persist, revert to r9 config.
// ---------------------------------------------------------------------------

__device__ __forceinline__ void load_lds16(const void* g, void* l) {
    __builtin_amdgcn_global_load_lds(
        (const __attribute__((address_space(1))) unsigned int*)g,
        (__attribute__((address_space(3))) unsigned int*)l, 16, 0, 0);
}

#define MFMA32 __builtin_amdgcn_mfma_f32_32x32x16_bf16

__global__ __launch_bounds__(512, 2) void gemm256_8ph(const __hip_bfloat16* __restrict__ A,
                                                      const __hip_bfloat16* __restrict__ B,
                                                      const float* __restrict__ bias,
                                                      float* __restrict__ C) {
    extern __shared__ __align__(16) char lds[];

    const int tid  = threadIdx.x;
    const int lane = tid & 63;
    const int wave = tid >> 6;

    // T1: XCD swizzle, 8x8 square chunk per XCD (512 wgs % 8 == 0, bijective).
    const int xcd = blockIdx.x & 7;
    const int w64 = blockIdx.x >> 3;               // 0..63 within XCD
    const int tm  = (xcd >> 1) * 8 + (w64 >> 3);   // 0..31 M-tiles
    const int tn  = (xcd & 1) * 8 + (w64 & 7);     // 0..15 N-tiles

    const __hip_bfloat16* Ab = A + (size_t)tm * 256 * IN_F;
    const __hip_bfloat16* Bb = B + (size_t)tn * 256 * IN_F;

    // Staging source (inverse of the bit-permuted layout; see header comment):
    const int srow = ((lane >> 2) & 15) + ((lane & 1) << 4) + ((wave >> 2) << 5);
    const int skc  = ((((lane >> 1) ^ (lane >> 5)) & 1) << 3) + ((wave & 3) << 4);
    const size_t off0 = (size_t)srow * IN_F + (size_t)skc;

    // Global source stream bases (per-lane, advance by scalar t-offset only)
    const __hip_bfloat16* qA0 = Ab + off0;
    const __hip_bfloat16* qA1 = Ab + (size_t)128 * IN_F + off0;
    const __hip_bfloat16* qB0 = Bb + off0;
    const __hip_bfloat16* qB1 = Bb + (size_t)128 * IN_F + off0;

    // Per-lane read offset (bit-permuted layout):
    // bit4 = l4, bit5 = l5^l3, bit6-9 = l0-3.
    const int flo32 = (lane & 16)
                    + (((((lane >> 5) ^ (lane >> 3)) & 1)) << 5)
                    + ((lane & 15) << 6);

    const int ah = wave >> 2;          // A half this wave reads (rows)
    const int bh = (wave >> 1) & 1;    // B half this wave reads (cols)

    // Pre-folded LDS read bases per buffer: every read is base + literal.
    const char* aRd[2] = { lds + ah * 16384 + flo32,
                           lds + 65536 + ah * 16384 + flo32 };
    const char* bRd[2] = { lds + 32768 + bh * 16384 + (wave & 1) * 8192 + flo32,
                           lds + 65536 + 32768 + bh * 16384 + (wave & 1) * 8192 + flo32 };

    const int wv1024 = wave * 1024;    // staging dest subtile base

#define STAGE2(ps, te, LO) do {                                             \
        const __hip_bfloat16* g_ = (ps) + (te);                             \
        load_lds16(g_,              lds + (LO) + wv1024);                   \
        load_lds16(g_ + 64 * IN_F,  lds + (LO) + 8192 + wv1024);            \
    } while (0)

    // ---- prologue: B0(0) B1(0) A0(0) A1(0) B0(1) B1(1)  (12 loads) ----
    STAGE2(qB0, 0,  32768);
    STAGE2(qB1, 0,  49152);
    STAGE2(qA0, 0,  0);
    STAGE2(qA1, 0,  16384);
    STAGE2(qB0, 64, 65536 + 32768);
    STAGE2(qB1, 64, 65536 + 49152);
    asm volatile("s_waitcnt vmcnt(4)" ::: "memory");   // tile0 landed; B(1) in flight
    __builtin_amdgcn_s_barrier();

    short8 aF[2][4], bA[4], bB[4];
    f32x16 acc[4][2] = {};

#define TILE(T, CBI) do {                                                          \
        const int t1e = (((T) + 1) & 63) << 6;   /* elem offset of tile T+1 */     \
        const int t2e = (((T) + 2) & 63) << 6;                                     \
        /* ---------- phase 0: quadrant (rb01, cb0) ---------- */                  \
        _Pragma("unroll")                                                          \
        for (int i = 0; i < 2; ++i)                                                \
            _Pragma("unroll")                                                      \
            for (int ks = 0; ks < 4; ++ks)                                         \
                aF[i][ks] = *(const short8*)(aRd[CBI] + i * 4096 + ks * 1024);     \
        _Pragma("unroll")                                                          \
        for (int ks = 0; ks < 4; ++ks)                                             \
            bA[ks] = *(const short8*)(bRd[CBI] + ks * 1024);                       \
        STAGE2(qA0, t1e, ((CBI) ^ 1) * 65536);                                     \
        __builtin_amdgcn_s_barrier();                                              \
        __builtin_amdgcn_s_setprio(1);                                             \
        _Pragma("unroll")                                                          \
        for (int ks = 0; ks < 4; ++ks) {                                           \
            acc[0][0] = MFMA32(aF[0][ks], bA[ks], acc[0][0], 0, 0, 0);             \
            acc[1][0] = MFMA32(aF[1][ks], bA[ks], acc[1][0], 0, 0, 0);             \
        }                                                                          \
        __builtin_amdgcn_s_setprio(0);                                             \
        __builtin_amdgcn_s_barrier();                                              \
        /* ---------- phase 1: quadrant (rb01, cb1) ---------- */                  \
        _Pragma("unroll")                                                          \
        for (int ks = 0; ks < 4; ++ks)                                             \
            bB[ks] = *(const short8*)(bRd[CBI] + 4096 + ks * 1024);                \
        STAGE2(qA1, t1e, ((CBI) ^ 1) * 65536 + 16384);                             \
        __builtin_amdgcn_s_barrier();                                              \
        __builtin_amdgcn_s_setprio(1);                                             \
        _Pragma("unroll")                                                          \
        for (int ks = 0; ks < 4; ++ks) {                                           \
            acc[0][1] = MFMA32(aF[0][ks], bB[ks], acc[0][1], 0, 0, 0);             \
            acc[1][1] = MFMA32(aF[1][ks], bB[ks], acc[1][1], 0, 0, 0);             \
        }                                                                          \
        __builtin_amdgcn_s_setprio(0);                                             \
        __builtin_amdgcn_s_barrier();                                              \
        /* ---------- phase 2: quadrant (rb23, cb1) ---------- */                  \
        _Pragma("unroll")                                                          \
        for (int i = 0; i < 2; ++i)                                                \
            _Pragma("unroll")                                                      \
            for (int ks = 0; ks < 4; ++ks)                                         \
                aF[i][ks] = *(const short8*)(aRd[CBI] + 8192 + i * 4096 + ks * 1024);\
        STAGE2(qB0, t2e, (CBI) * 65536 + 32768);   /* cur-B dead after ph1 */      \
        __builtin_amdgcn_s_barrier();                                              \
        __builtin_amdgcn_s_setprio(1);                                             \
        _Pragma("unroll")                                                          \
        for (int ks = 0; ks < 4; ++ks) {                                           \
            acc[2][1] = MFMA32(aF[0][ks], bB[ks], acc[2][1], 0, 0, 0);             \
            acc[3][1] = MFMA32(aF[1][ks], bB[ks], acc[3][1], 0, 0, 0);             \
        }                                                                          \
        __builtin_amdgcn_s_setprio(0);                                             \
        __builtin_amdgcn_s_barrier();                                              \
        /* ---------- phase 3: quadrant (rb23, cb0) ---------- */                  \
        STAGE2(qB1, t2e, (CBI) * 65536 + 49152);                                   \
        asm volatile("s_waitcnt vmcnt(4)" ::: "memory");  /* tile T+1 landed */    \
        __builtin_amdgcn_s_barrier();                     /* publish to all */     \
        __builtin_amdgcn_s_setprio(1);                                             \
        _Pragma("unroll")                                                          \
        for (int ks = 0; ks < 4; ++ks) {                                           \
            acc[2][0] = MFMA32(aF[0][ks], bA[ks], acc[2][0], 0, 0, 0);             \
            acc[3][0] = MFMA32(aF[1][ks], bA[ks], acc[3][0], 0, 0, 0);             \
        }                                                                          \
        __builtin_amdgcn_s_setprio(0);                                             \
        __builtin_amdgcn_s_barrier();                                              \
    } while (0)

    for (int tt = 0; tt < 32; ++tt) {      // 2 K-tiles per iter: literal buffers
        TILE(2 * tt,     0);
        TILE(2 * tt + 1, 1);
    }
    asm volatile("s_waitcnt vmcnt(0)" ::: "memory");  // drain wrapped prefetches

    // ---- epilogue (r10-verified): 32x32 C/D: col = lane&31,
    //      row = (reg&3) + 8*(reg>>2) + 4*(lane>>5); fuse bias. ----
    const int cl = lane & 31;
    const int hi = lane >> 5;
    const size_t m_base = (size_t)tm * 256 + (size_t)ah * 128 + hi * 4;
    const int    n_base = tn * 256 + (wave & 3) * 64;
#pragma unroll
    for (int cb = 0; cb < 2; ++cb) {
        const int n = n_base + cb * 32 + cl;
        const float bv = bias[n];
#pragma unroll
        for (int rb = 0; rb < 4; ++rb) {
#pragma unroll
            for (int g = 0; g < 4; ++g) {
                const size_t m0 = m_base + rb * 32 + g * 8;
#pragma unroll
                for (int rr = 0; rr < 4; ++rr)
                    __builtin_nontemporal_store(acc[rb][cb][g * 4 + rr] + bv,
                                                &C[(m0 + rr) * OUT_F + n]);
            }
        }
    }
#undef STAGE2
#undef TILE
}

// ---------------------------------------------------------------------------
extern "C" void kernel_launch(void* const* d_in, const int* in_sizes, int n_in,
                              void* d_out, int out_size, void* d_ws, size_t ws_size,
                              hipStream_t stream) {
    const float* x    = (const float*)d_in[0];   // [4,2048,4096] fp32
    const int*   qc   = (const int*)d_in[1];     // [4096,4096] int32 codes
    const float* sc   = (const float*)d_in[2];   // [4096,64] fp32
    const float* bias = (const float*)d_in[3];   // [4096]
    const float* lA   = (const float*)d_in[4];   // [16,4096]
    const float* lB   = (const float*)d_in[5];   // [4096,16]
    float* out = (float*)d_out;                  // [4,2048,4096] fp32

    // workspace: x_bf16 (64 MB) + W'_bf16 (32 MB) = 96 MB
    __hip_bfloat16* xb = (__hip_bfloat16*)d_ws;
    __hip_bfloat16* wb = xb + (size_t)M_TOK * IN_F;

    // allow 128 KiB dynamic LDS for the 8-phase GEMM (host-side, capture-safe)
    static bool attr_done = false;
    if (!attr_done) {
        (void)hipFuncSetAttribute((const void*)gemm256_8ph,
                                  hipFuncAttributeMaxDynamicSharedMemorySize, 131072);
        attr_done = true;
    }

    cvt_x<<<2048, 256, 0, stream>>>(x, xb);
    dequant_lora<<<2048, 256, 0, stream>>>(qc, sc, lA, lB, wb);
    gemm256_8ph<<<dim3(512), dim3(512), 131072, stream>>>(xb, wb, bias, out);
}